// Round 2
// baseline (89.513 us; speedup 1.0000x reference)
//
#include <hip/hip_runtime.h>
#include <hip/hip_bf16.h>
#include <stdint.h>

// Problem dims (fixed by reference):
//  encoder_output: (4,256,512) f32   -> 1024 rows x 512
//  decoder_output: (4,64,512)  f32   ->  256 rows x 512
//  W: (1024,1024) f32, b: (1024,) f32
//  out: (4,256,64,1024) f32 log_softmax(enc_proj[bt] + dec_proj[b,u] + b)

#define KDIM 512
#define NV   1024
#define WDIM 1024

typedef __attribute__((ext_vector_type(8))) short short8;   // 8 bf16
typedef __attribute__((ext_vector_type(4))) float f32x4;

__device__ __forceinline__ ushort f2bf(float f) {
    uint32_t u = __float_as_uint(f);
    uint32_t r = (u + 0x7fffu + ((u >> 16) & 1u)) >> 16;  // RNE
    return (ushort)r;
}

__global__ void cvt_bf16(const float* __restrict__ src, ushort* __restrict__ dst, int n4) {
    int i = blockIdx.x * blockDim.x + threadIdx.x;
    if (i >= n4) return;
    float4 v = reinterpret_cast<const float4*>(src)[i];
    ushort4 h;
    h.x = f2bf(v.x); h.y = f2bf(v.y); h.z = f2bf(v.z); h.w = f2bf(v.w);
    reinterpret_cast<ushort4*>(dst)[i] = h;
}

// out[M][1024] = A[M][512](bf16) . W[:, wcol_off:+512]^T (+ bias)
// 64x64 tile per block, 4 waves (2x2), each wave 32x32 via 2x2 16x16x32 mfma.
// Operands fetched directly from global (L2-resident at this size).
__global__ __launch_bounds__(256) void gemm_proj(
        const ushort* __restrict__ A, const ushort* __restrict__ Wb,
        const float* __restrict__ bias, float* __restrict__ out, int wcol_off) {
    int tid = threadIdx.x;
    int lane = tid & 63, wid = tid >> 6;
    int wr = wid >> 1, wc = wid & 1;
    int bm = blockIdx.y * 64, bn = blockIdx.x * 64;
    int r16 = lane & 15, kg = lane >> 4;   // A/B frag: row/col = lane&15, k = kg*8..+8

    const ushort* a0p = A  + (size_t)(bm + wr * 32 + r16) * KDIM + kg * 8;
    const ushort* a1p = a0p + 16 * KDIM;
    const ushort* b0p = Wb + (size_t)(bn + wc * 32 + r16) * WDIM + wcol_off + kg * 8;
    const ushort* b1p = b0p + 16 * WDIM;

    f32x4 acc00 = {}, acc01 = {}, acc10 = {}, acc11 = {};
    #pragma unroll
    for (int ks = 0; ks < KDIM; ks += 32) {
        short8 a0 = *(const short8*)(a0p + ks);
        short8 a1 = *(const short8*)(a1p + ks);
        short8 b0 = *(const short8*)(b0p + ks);
        short8 b1 = *(const short8*)(b1p + ks);
        acc00 = __builtin_amdgcn_mfma_f32_16x16x32_bf16(a0, b0, acc00, 0, 0, 0);
        acc01 = __builtin_amdgcn_mfma_f32_16x16x32_bf16(a0, b1, acc01, 0, 0, 0);
        acc10 = __builtin_amdgcn_mfma_f32_16x16x32_bf16(a1, b0, acc10, 0, 0, 0);
        acc11 = __builtin_amdgcn_mfma_f32_16x16x32_bf16(a1, b1, acc11, 0, 0, 0);
    }

    // C/D layout (m89-verified): col = lane&15, row = (lane>>4)*4 + reg
    int mb = bm + wr * 32 + (lane >> 4) * 4;
    int nb = bn + wc * 32 + (lane & 15);
    #pragma unroll
    for (int i = 0; i < 2; ++i) {
        #pragma unroll
        for (int j = 0; j < 2; ++j) {
            f32x4 acc = (i == 0) ? (j == 0 ? acc00 : acc01) : (j == 0 ? acc10 : acc11);
            int n = nb + j * 16;
            float bv = bias ? bias[n] : 0.0f;
            #pragma unroll
            for (int r = 0; r < 4; ++r) {
                int m = mb + i * 16 + r;
                out[(size_t)m * NV + n] = acc[r] + bv;
            }
        }
    }
}

// One block per output row (b,t,u): logits = encp[bt] + decp[b*64+u]; write log_softmax.
__global__ __launch_bounds__(256) void lse_kernel(
        const float* __restrict__ encp, const float* __restrict__ decp,
        float* __restrict__ out) {
    int r = blockIdx.x;          // ((b*256+t)*64+u)
    int bt = r >> 6;
    int u = r & 63;
    int b = bt >> 8;
    int drow = (b << 6) | u;
    int tid = threadIdx.x;

    float4 e = reinterpret_cast<const float4*>(encp + (size_t)bt * NV)[tid];
    float4 d = reinterpret_cast<const float4*>(decp + (size_t)drow * NV)[tid];
    float x0 = e.x + d.x, x1 = e.y + d.y, x2 = e.z + d.z, x3 = e.w + d.w;

    __shared__ float red[8];
    int lane = tid & 63, wave = tid >> 6;

    float m = fmaxf(fmaxf(x0, x1), fmaxf(x2, x3));
    #pragma unroll
    for (int off = 32; off >= 1; off >>= 1)
        m = fmaxf(m, __shfl_xor(m, off, 64));
    if (lane == 0) red[wave] = m;
    __syncthreads();
    m = fmaxf(fmaxf(red[0], red[1]), fmaxf(red[2], red[3]));

    float s = __expf(x0 - m) + __expf(x1 - m) + __expf(x2 - m) + __expf(x3 - m);
    #pragma unroll
    for (int off = 32; off >= 1; off >>= 1)
        s += __shfl_xor(s, off, 64);
    if (lane == 0) red[4 + wave] = s;
    __syncthreads();
    float lse = m + __logf(red[4] + red[5] + red[6] + red[7]);

    float4 o = {x0 - lse, x1 - lse, x2 - lse, x3 - lse};
    reinterpret_cast<float4*>(out + (size_t)r * NV)[tid] = o;
}

extern "C" void kernel_launch(void* const* d_in, const int* in_sizes, int n_in,
                              void* d_out, int out_size, void* d_ws, size_t ws_size,
                              hipStream_t stream) {
    const float* enc = (const float*)d_in[0];   // 524288
    const float* dec = (const float*)d_in[1];   // 131072
    const float* W   = (const float*)d_in[2];   // 1048576
    const float* b   = (const float*)d_in[3];   // 1024
    float* out = (float*)d_out;

    char* ws = (char*)d_ws;
    float*  encp = (float*)(ws + 0);            // 1024*1024*4 = 4 MiB
    float*  decp = (float*)(ws + 4194304);      //  256*1024*4 = 1 MiB
    ushort* encb = (ushort*)(ws + 5242880);     // 524288*2   = 1 MiB
    ushort* decb = (ushort*)(ws + 6291456);     // 131072*2
    ushort* wb   = (ushort*)(ws + 6553600);     // 1048576*2  = 2 MiB  (end ~8.25 MiB)

    cvt_bf16<<<512,  256, 0, stream>>>(enc, encb, 131072);
    cvt_bf16<<<128,  256, 0, stream>>>(dec, decb, 32768);
    cvt_bf16<<<1024, 256, 0, stream>>>(W,   wb,   262144);

    gemm_proj<<<dim3(16, 16), 256, 0, stream>>>(encb, wb, b,       encp, 0);
    gemm_proj<<<dim3(16, 4),  256, 0, stream>>>(decb, wb, nullptr, decp, 512);

    lse_kernel<<<65536, 256, 0, stream>>>(encp, decp, out);
}

// Round 4
// 71.414 us; speedup vs baseline: 1.2534x; 1.2534x over previous
//
#include <hip/hip_runtime.h>
#include <hip/hip_bf16.h>
#include <stdint.h>

// Problem dims (fixed by reference):
//  encoder_output: (4,256,512) f32   -> 1024 rows x 512
//  decoder_output: (4,64,512)  f32   ->  256 rows x 512
//  W: (1024,1024) f32, b: (1024,) f32
//  out: (4,256,64,1024) f32 log_softmax(enc_proj[bt] + dec_proj[b,u] + b)

#define KDIM 512
#define NV   1024
#define WDIM 1024

typedef __attribute__((ext_vector_type(8))) short short8;   // 8 bf16
typedef __attribute__((ext_vector_type(4))) float f32x4;

__device__ __forceinline__ ushort f2bf(float f) {
    uint32_t u = __float_as_uint(f);
    uint32_t r = (u + 0x7fffu + ((u >> 16) & 1u)) >> 16;  // RNE
    return (ushort)r;
}

// One fused conversion kernel: blocks [0,512) enc, [512,640) dec, [640,1664) W.
__global__ __launch_bounds__(256) void cvt_all(
        const float* __restrict__ enc, const float* __restrict__ dec,
        const float* __restrict__ W,
        ushort* __restrict__ encb, ushort* __restrict__ decb, ushort* __restrict__ wb) {
    int blk = blockIdx.x;
    const float* src; ushort* dst; int i;
    if (blk < 512)      { src = enc; dst = encb; i = blk * 256 + threadIdx.x; }
    else if (blk < 640) { src = dec; dst = decb; i = (blk - 512) * 256 + threadIdx.x; }
    else                { src = W;   dst = wb;   i = (blk - 640) * 256 + threadIdx.x; }
    float4 v = reinterpret_cast<const float4*>(src)[i];
    ushort4 h;
    h.x = f2bf(v.x); h.y = f2bf(v.y); h.z = f2bf(v.z); h.w = f2bf(v.w);
    reinterpret_cast<ushort4*>(dst)[i] = h;
}

// Both projections in one launch.
// blockIdx.y < 16: enc rows (M=1024), W cols [0,512), +bias -> encp
// blockIdx.y >= 16: dec rows (M=256), W cols [512,1024), no bias -> decp
// 64x64 tile per block, 4 waves (2x2), each wave 32x32 via 2x2 16x16x32 mfma.
// Operands fetched directly from global (L2-resident at this size).
__global__ __launch_bounds__(256) void gemm_proj(
        const ushort* __restrict__ encA, const ushort* __restrict__ decA,
        const ushort* __restrict__ Wb, const float* __restrict__ bias,
        float* __restrict__ encp, float* __restrict__ decp) {
    int tid = threadIdx.x;
    int lane = tid & 63, wid = tid >> 6;
    int wr = wid >> 1, wc = wid & 1;

    const ushort* A; float* out; int wcol_off, bm; bool use_bias;
    if (blockIdx.y < 16) { A = encA; out = encp; wcol_off = 0;   bm = blockIdx.y * 64;        use_bias = true;  }
    else                 { A = decA; out = decp; wcol_off = 512; bm = (blockIdx.y - 16) * 64; use_bias = false; }
    int bn = blockIdx.x * 64;
    int r16 = lane & 15, kg = lane >> 4;   // A/B frag: row/col = lane&15, k = kg*8..+8

    const ushort* a0p = A  + (size_t)(bm + wr * 32 + r16) * KDIM + kg * 8;
    const ushort* a1p = a0p + 16 * KDIM;
    const ushort* b0p = Wb + (size_t)(bn + wc * 32 + r16) * WDIM + wcol_off + kg * 8;
    const ushort* b1p = b0p + 16 * WDIM;

    f32x4 acc00 = {}, acc01 = {}, acc10 = {}, acc11 = {};
    #pragma unroll
    for (int ks = 0; ks < KDIM; ks += 32) {
        short8 a0 = *(const short8*)(a0p + ks);
        short8 a1 = *(const short8*)(a1p + ks);
        short8 b0 = *(const short8*)(b0p + ks);
        short8 b1 = *(const short8*)(b1p + ks);
        acc00 = __builtin_amdgcn_mfma_f32_16x16x32_bf16(a0, b0, acc00, 0, 0, 0);
        acc01 = __builtin_amdgcn_mfma_f32_16x16x32_bf16(a0, b1, acc01, 0, 0, 0);
        acc10 = __builtin_amdgcn_mfma_f32_16x16x32_bf16(a1, b0, acc10, 0, 0, 0);
        acc11 = __builtin_amdgcn_mfma_f32_16x16x32_bf16(a1, b1, acc11, 0, 0, 0);
    }

    // C/D layout (m89-verified): col = lane&15, row = (lane>>4)*4 + reg
    int mb = bm + wr * 32 + (lane >> 4) * 4;
    int nb = bn + wc * 32 + (lane & 15);
    #pragma unroll
    for (int i = 0; i < 2; ++i) {
        #pragma unroll
        for (int j = 0; j < 2; ++j) {
            f32x4 acc = (i == 0) ? (j == 0 ? acc00 : acc01) : (j == 0 ? acc10 : acc11);
            int n = nb + j * 16;
            float bv = use_bias ? bias[n] : 0.0f;
            #pragma unroll
            for (int r = 0; r < 4; ++r) {
                int m = mb + i * 16 + r;
                out[(size_t)m * NV + n] = acc[r] + bv;
            }
        }
    }
}

// Wave-per-row log_softmax. Each wave owns one bt's enc row (16 f32/lane in
// registers) and iterates 8 u-values; no LDS, no barriers, shfl reductions.
// waves total = 65536 rows / 8 = 8192; 4 waves/block -> 2048 blocks.
__global__ __launch_bounds__(256) void lse_kernel(
        const float* __restrict__ encp, const float* __restrict__ decp,
        float* __restrict__ out) {
    int tid = threadIdx.x;
    int lane = tid & 63;
    int w = blockIdx.x * 4 + (tid >> 6);   // wave id in [0, 8192)
    int bt = w >> 3;                       // enc row, [0, 1024)
    int ug = w & 7;                        // u-group of 8
    int b = bt >> 8;

    const float* ep = encp + (size_t)bt * NV + lane * 4;
    float4 e0 = *(const float4*)(ep + 0);
    float4 e1 = *(const float4*)(ep + 256);
    float4 e2 = *(const float4*)(ep + 512);
    float4 e3 = *(const float4*)(ep + 768);

    #pragma unroll
    for (int uu = 0; uu < 8; ++uu) {
        int u = ug * 8 + uu;
        const float* dp = decp + (size_t)((b << 6) | u) * NV + lane * 4;
        float4 d0 = *(const float4*)(dp + 0);
        float4 d1 = *(const float4*)(dp + 256);
        float4 d2 = *(const float4*)(dp + 512);
        float4 d3 = *(const float4*)(dp + 768);
        float x[16];
        x[0]=e0.x+d0.x; x[1]=e0.y+d0.y; x[2]=e0.z+d0.z; x[3]=e0.w+d0.w;
        x[4]=e1.x+d1.x; x[5]=e1.y+d1.y; x[6]=e1.z+d1.z; x[7]=e1.w+d1.w;
        x[8]=e2.x+d2.x; x[9]=e2.y+d2.y; x[10]=e2.z+d2.z; x[11]=e2.w+d2.w;
        x[12]=e3.x+d3.x; x[13]=e3.y+d3.y; x[14]=e3.z+d3.z; x[15]=e3.w+d3.w;

        float m = x[0];
        #pragma unroll
        for (int i = 1; i < 16; ++i) m = fmaxf(m, x[i]);
        #pragma unroll
        for (int off = 32; off >= 1; off >>= 1)
            m = fmaxf(m, __shfl_xor(m, off, 64));

        float s = 0.0f;
        #pragma unroll
        for (int i = 0; i < 16; ++i) s += __expf(x[i] - m);
        #pragma unroll
        for (int off = 32; off >= 1; off >>= 1)
            s += __shfl_xor(s, off, 64);
        float lse = m + __logf(s);

        float* op = out + (size_t)((bt << 6) | u) * NV + lane * 4;
        float4 o;
        o.x=x[0]-lse;  o.y=x[1]-lse;  o.z=x[2]-lse;  o.w=x[3]-lse;  *(float4*)(op + 0)   = o;
        o.x=x[4]-lse;  o.y=x[5]-lse;  o.z=x[6]-lse;  o.w=x[7]-lse;  *(float4*)(op + 256) = o;
        o.x=x[8]-lse;  o.y=x[9]-lse;  o.z=x[10]-lse; o.w=x[11]-lse; *(float4*)(op + 512) = o;
        o.x=x[12]-lse; o.y=x[13]-lse; o.z=x[14]-lse; o.w=x[15]-lse; *(float4*)(op + 768) = o;
    }
}

extern "C" void kernel_launch(void* const* d_in, const int* in_sizes, int n_in,
                              void* d_out, int out_size, void* d_ws, size_t ws_size,
                              hipStream_t stream) {
    const float* enc = (const float*)d_in[0];   // 524288
    const float* dec = (const float*)d_in[1];   // 131072
    const float* W   = (const float*)d_in[2];   // 1048576
    const float* b   = (const float*)d_in[3];   // 1024
    float* out = (float*)d_out;

    char* ws = (char*)d_ws;
    float*  encp = (float*)(ws + 0);            // 1024*1024*4 = 4 MiB
    float*  decp = (float*)(ws + 4194304);      //  256*1024*4 = 1 MiB
    ushort* encb = (ushort*)(ws + 5242880);     // 524288*2   = 1 MiB
    ushort* decb = (ushort*)(ws + 6291456);     // 131072*2
    ushort* wb   = (ushort*)(ws + 6553600);     // 1048576*2  = 2 MiB  (end ~8.25 MiB)

    cvt_all<<<1664, 256, 0, stream>>>(enc, dec, W, encb, decb, wb);
    gemm_proj<<<dim3(16, 20), 256, 0, stream>>>(encb, decb, wb, b, encp, decp);
    lse_kernel<<<2048, 256, 0, stream>>>(encp, decp, out);
}